// Round 1
// baseline (359.025 us; speedup 1.0000x reference)
//
#include <hip/hip_runtime.h>

#define BASE_BITS 17

// Detect whether integer inputs are int64 (JAX x64 enabled) or int32 (default).
// Tokens are < 2^17, so an int64 layout has all-zero high words; 256 random
// int32 tokens being all zero has probability ~ (2e-5)^256 ~ 0.
__global__ void detect_dtype_kernel(const unsigned int* __restrict__ xw,
                                    int* __restrict__ flag) {
    __shared__ int nz;
    if (threadIdx.x == 0) nz = 0;
    __syncthreads();
    if (xw[2 * threadIdx.x + 1] != 0u) atomicOr(&nz, 1);
    __syncthreads();
    if (threadIdx.x == 0) *flag = (nz == 0) ? 1 : 0;  // 1 => int64 layout
}

template <typename K>
__device__ __forceinline__ int lower_bound(const K* __restrict__ keys, int n, K key) {
    int lo = 0, hi = n;
    while (lo < hi) {
        int mid = (lo + hi) >> 1;
        K v = keys[mid];
        if (v < key) lo = mid + 1; else hi = mid;
    }
    return lo;
}

template <typename K>
__device__ __forceinline__ K probe(const K* __restrict__ keys,
                                   const K* __restrict__ vals,
                                   int n, K key) {
    int idx = lower_bound(keys, n, key);
    if (idx >= n) idx = n - 1;           // jnp.clip(searchsorted, 0, n-1)
    return (keys[idx] == key) ? vals[idx] : (K)0;
}

__global__ __launch_bounds__(256) void ngram_lookup_kernel(
    const void* __restrict__ xv,
    const void* __restrict__ k2v, const void* __restrict__ v2v,
    const void* __restrict__ k3v, const void* __restrict__ v3v,
    void* __restrict__ outv,
    int n2, int n3, int S, int total, const int* __restrict__ flag)
{
    int gid = blockIdx.x * blockDim.x + threadIdx.x;
    if (gid >= total) return;
    int s = gid % S;  // position within row; rows are left-zero-padded

    if (*flag) {
        // ---- int64 path (JAX x64 enabled) ----
        const long long* x = (const long long*)xv;
        long long t2 = x[gid];
        long long t1 = (s >= 1) ? x[gid - 1] : 0ll;
        long long t0 = (s >= 2) ? x[gid - 2] : 0ll;
        long long e2 = (t1 << BASE_BITS) | t2;
        long long e3 = (((t0 << BASE_BITS) | t1) << BASE_BITS) | t2;
        long long* out = (long long*)outv;
        out[gid]         = probe((const long long*)k2v, (const long long*)v2v, n2, e2);
        out[total + gid] = probe((const long long*)k3v, (const long long*)v3v, n3, e3);
    } else {
        // ---- int32 path (JAX default: int64 silently downgraded, wraps mod 2^32) ----
        const int* x = (const int*)xv;
        unsigned t2 = (unsigned)x[gid];
        unsigned t1 = (s >= 1) ? (unsigned)x[gid - 1] : 0u;
        unsigned t0 = (s >= 2) ? (unsigned)x[gid - 2] : 0u;
        int e2 = (int)((t1 << BASE_BITS) | t2);
        int e3 = (int)((((t0 << BASE_BITS) | t1) << BASE_BITS) | t2);
        int* out = (int*)outv;
        out[gid]         = probe((const int*)k2v, (const int*)v2v, n2, e2);
        out[total + gid] = probe((const int*)k3v, (const int*)v3v, n3, e3);
    }
}

extern "C" void kernel_launch(void* const* d_in, const int* in_sizes, int n_in,
                              void* d_out, int out_size, void* d_ws, size_t ws_size,
                              hipStream_t stream) {
    // setup_inputs() dict order: x, keys2, vals2, keys3, vals3
    const void* x  = d_in[0];
    const void* k2 = d_in[1];
    const void* v2 = d_in[2];
    const void* k3 = d_in[3];
    const void* v3 = d_in[4];
    int n2 = in_sizes[1];
    int n3 = in_sizes[3];
    int total = in_sizes[0];     // B * S = 4,194,304
    int S = 16384;               // sequence length (per reference)

    int* flag = (int*)d_ws;
    detect_dtype_kernel<<<1, 256, 0, stream>>>((const unsigned int*)x, flag);

    int block = 256;
    int grid = (total + block - 1) / block;
    ngram_lookup_kernel<<<grid, block, 0, stream>>>(
        x, k2, v2, k3, v3, d_out, n2, n3, S, total, flag);
}

// Round 2
// 129.003 us; speedup vs baseline: 2.7831x; 2.7831x over previous
//
#include <hip/hip_runtime.h>

#define BASE_BITS 17
#define HASH_LOG 18
#define HASH_SIZE (1u << HASH_LOG)
#define HASH_MASK (HASH_SIZE - 1u)

__device__ __forceinline__ unsigned hash32(unsigned k) {
    return (k * 2654435761u) >> (32 - HASH_LOG);
}

// ---------------- dtype detect (int64 layout has zero high words) ----------
__global__ void detect_dtype_kernel(const unsigned int* __restrict__ xw,
                                    int* __restrict__ flag) {
    __shared__ int nz;
    if (threadIdx.x == 0) nz = 0;
    __syncthreads();
    if (xw[2 * threadIdx.x + 1] != 0u) atomicOr(&nz, 1);
    __syncthreads();
    if (threadIdx.x == 0) *flag = (nz == 0) ? 1 : 0;  // 1 => int64 layout
}

// ---------------- hash table build ----------------------------------------
__global__ void zero_tables_kernel(unsigned long long* __restrict__ t, int n) {
    int i = blockIdx.x * blockDim.x + threadIdx.x;
    int stride = gridDim.x * blockDim.x;
    for (; i < n; i += stride) t[i] = 0ull;
}

__global__ void build_hash_kernel(const int* __restrict__ keys,
                                  const int* __restrict__ vals, int n,
                                  unsigned long long* __restrict__ table) {
    int i = blockIdx.x * blockDim.x + threadIdx.x;
    if (i >= n) return;
    unsigned k = (unsigned)keys[i];
    unsigned long long packed = ((unsigned long long)k << 32) | (unsigned)vals[i];
    unsigned slot = hash32(k);
    while (atomicCAS(&table[slot], 0ull, packed) != 0ull)
        slot = (slot + 1u) & HASH_MASK;
}

// ---------------- binary-search fallback ----------------------------------
template <typename K>
__device__ __forceinline__ int lower_bound(const K* __restrict__ keys, int n, K key) {
    int lo = 0, hi = n;
    while (lo < hi) {
        int mid = (lo + hi) >> 1;
        if (keys[mid] < key) lo = mid + 1; else hi = mid;
    }
    return lo;
}

template <typename K>
__device__ __forceinline__ K bprobe(const K* __restrict__ keys,
                                    const K* __restrict__ vals, int n, K key) {
    int idx = lower_bound(keys, n, key);
    if (idx >= n) idx = n - 1;
    return (keys[idx] == key) ? vals[idx] : (K)0;
}

// ---------------- main lookup: hash path (int32) + int64 fallback ----------
__global__ __launch_bounds__(256) void ngram_hash_kernel(
    const void* __restrict__ xv,
    const unsigned long long* __restrict__ tab2,
    const unsigned long long* __restrict__ tab3,
    const void* __restrict__ k2v, const void* __restrict__ v2v,
    const void* __restrict__ k3v, const void* __restrict__ v3v,
    void* __restrict__ outv,
    int n2, int n3, int S, int total, const int* __restrict__ flag)
{
    int gid = blockIdx.x * blockDim.x + threadIdx.x;
    if (gid >= total) return;
    int s = gid & (S - 1);  // S is a power of two (16384)

    if (*flag) {
        // int64 layout (x64-enabled harness): binary-search path
        const long long* x = (const long long*)xv;
        long long t2 = x[gid];
        long long t1 = (s >= 1) ? x[gid - 1] : 0ll;
        long long t0 = (s >= 2) ? x[gid - 2] : 0ll;
        long long e2 = (t1 << BASE_BITS) | t2;
        long long e3 = (((t0 << BASE_BITS) | t1) << BASE_BITS) | t2;
        long long* out = (long long*)outv;
        out[gid]         = bprobe((const long long*)k2v, (const long long*)v2v, n2, e2);
        out[total + gid] = bprobe((const long long*)k3v, (const long long*)v3v, n3, e3);
        return;
    }

    const int* x = (const int*)xv;
    unsigned t2 = (unsigned)x[gid];
    unsigned t1 = (s >= 1) ? (unsigned)x[gid - 1] : 0u;
    unsigned t0 = (s >= 2) ? (unsigned)x[gid - 2] : 0u;
    unsigned e2 = (t1 << BASE_BITS) | t2;
    unsigned e3 = (((t0 << BASE_BITS) | t1) << BASE_BITS) | t2;

    // issue both initial probe loads back-to-back so the chains overlap
    unsigned s2 = hash32(e2), s3 = hash32(e3);
    unsigned long long w2 = tab2[s2], w3 = tab3[s3];

    int r2 = 0;
    for (;;) {
        if (w2 == 0ull) { r2 = 0; break; }
        if ((unsigned)(w2 >> 32) == e2) { r2 = (int)(unsigned)w2; break; }
        s2 = (s2 + 1u) & HASH_MASK;
        w2 = tab2[s2];
    }
    int r3 = 0;
    for (;;) {
        if (w3 == 0ull) { r3 = 0; break; }
        if ((unsigned)(w3 >> 32) == e3) { r3 = (int)(unsigned)w3; break; }
        s3 = (s3 + 1u) & HASH_MASK;
        w3 = tab3[s3];
    }

    int* out = (int*)outv;
    out[gid]         = r2;
    out[total + gid] = r3;
}

// Full binary-search kernel (used only if ws too small for hash tables)
__global__ __launch_bounds__(256) void ngram_bsearch_kernel(
    const void* __restrict__ xv,
    const void* __restrict__ k2v, const void* __restrict__ v2v,
    const void* __restrict__ k3v, const void* __restrict__ v3v,
    void* __restrict__ outv,
    int n2, int n3, int S, int total, const int* __restrict__ flag)
{
    int gid = blockIdx.x * blockDim.x + threadIdx.x;
    if (gid >= total) return;
    int s = gid & (S - 1);
    if (*flag) {
        const long long* x = (const long long*)xv;
        long long t2 = x[gid];
        long long t1 = (s >= 1) ? x[gid - 1] : 0ll;
        long long t0 = (s >= 2) ? x[gid - 2] : 0ll;
        long long e2 = (t1 << BASE_BITS) | t2;
        long long e3 = (((t0 << BASE_BITS) | t1) << BASE_BITS) | t2;
        long long* out = (long long*)outv;
        out[gid]         = bprobe((const long long*)k2v, (const long long*)v2v, n2, e2);
        out[total + gid] = bprobe((const long long*)k3v, (const long long*)v3v, n3, e3);
    } else {
        const int* x = (const int*)xv;
        unsigned t2 = (unsigned)x[gid];
        unsigned t1 = (s >= 1) ? (unsigned)x[gid - 1] : 0u;
        unsigned t0 = (s >= 2) ? (unsigned)x[gid - 2] : 0u;
        int e2 = (int)((t1 << BASE_BITS) | t2);
        int e3 = (int)((((t0 << BASE_BITS) | t1) << BASE_BITS) | t2);
        int* out = (int*)outv;
        out[gid]         = bprobe((const int*)k2v, (const int*)v2v, n2, e2);
        out[total + gid] = bprobe((const int*)k3v, (const int*)v3v, n3, e3);
    }
}

extern "C" void kernel_launch(void* const* d_in, const int* in_sizes, int n_in,
                              void* d_out, int out_size, void* d_ws, size_t ws_size,
                              hipStream_t stream) {
    const void* x  = d_in[0];
    const void* k2 = d_in[1];
    const void* v2 = d_in[2];
    const void* k3 = d_in[3];
    const void* v3 = d_in[4];
    int n2 = in_sizes[1];
    int n3 = in_sizes[3];
    int total = in_sizes[0];     // B * S = 4,194,304
    int S = 16384;

    int* flag = (int*)d_ws;
    detect_dtype_kernel<<<1, 256, 0, stream>>>((const unsigned int*)x, flag);

    size_t table_bytes = (size_t)HASH_SIZE * sizeof(unsigned long long);
    size_t need = 256 + 2 * table_bytes;

    int block = 256;
    int grid = (total + block - 1) / block;

    if (ws_size >= need) {
        unsigned long long* tab2 =
            (unsigned long long*)((char*)d_ws + 256);
        unsigned long long* tab3 = tab2 + HASH_SIZE;

        zero_tables_kernel<<<1024, 256, 0, stream>>>(tab2, (int)(2 * HASH_SIZE));
        build_hash_kernel<<<(n2 + 255) / 256, 256, 0, stream>>>(
            (const int*)k2, (const int*)v2, n2, tab2);
        build_hash_kernel<<<(n3 + 255) / 256, 256, 0, stream>>>(
            (const int*)k3, (const int*)v3, n3, tab3);

        ngram_hash_kernel<<<grid, block, 0, stream>>>(
            x, tab2, tab3, k2, v2, k3, v3, d_out, n2, n3, S, total, flag);
    } else {
        ngram_bsearch_kernel<<<grid, block, 0, stream>>>(
            x, k2, v2, k3, v3, d_out, n2, n3, S, total, flag);
    }
}

// Round 3
// 117.072 us; speedup vs baseline: 3.0667x; 1.1019x over previous
//
#include <hip/hip_runtime.h>

#define BASE_BITS 17
#define BUCKET_LOG 16
#define NBUCKETS (1u << BUCKET_LOG)          // 65536 buckets of 4 slots
#define NSLOTS (NBUCKETS * 4u)               // 2^18 slots, 1MB keys per table
#define SLOT_MASK (NSLOTS - 1u)
#define BUCKET_MASK (NBUCKETS - 1u)
#define EMPTY 0xFFFFFFFFu

__device__ __forceinline__ unsigned bucket_of(unsigned k) {
    return (k * 2654435761u) >> (32 - BUCKET_LOG);
}

// ---------------- dtype detect (int64 layout has zero high words) ----------
__global__ void detect_dtype_kernel(const unsigned int* __restrict__ xw,
                                    int* __restrict__ flags) {
    __shared__ int nz;
    if (threadIdx.x == 0) nz = 0;
    __syncthreads();
    if (xw[2 * threadIdx.x + 1] != 0u) atomicOr(&nz, 1);
    __syncthreads();
    if (threadIdx.x == 0) {
        flags[0] = (nz == 0) ? 1 : 0;  // 1 => int64 layout
        flags[1] = 0;                  // sentinel-collision fallback flag
    }
}

// ---------------- key-table init (fill with EMPTY) -------------------------
__global__ void init_keys_kernel(uint4* __restrict__ t, int n4) {
    int i = blockIdx.x * blockDim.x + threadIdx.x;
    int stride = gridDim.x * blockDim.x;
    uint4 e = make_uint4(EMPTY, EMPTY, EMPTY, EMPTY);
    for (; i < n4; i += stride) t[i] = e;
}

// ---------------- merged hash build ----------------------------------------
__global__ void build_hash_kernel(const int* __restrict__ keys2,
                                  const int* __restrict__ vals2, int n2,
                                  const int* __restrict__ keys3,
                                  const int* __restrict__ vals3, int n3,
                                  unsigned* __restrict__ K2, int* __restrict__ V2,
                                  unsigned* __restrict__ K3, int* __restrict__ V3,
                                  int* __restrict__ flags) {
    int i = blockIdx.x * blockDim.x + threadIdx.x;
    const int* keys; const int* vals; unsigned* K; int* V; int idx;
    if (i < n2)           { keys = keys2; vals = vals2; K = K2; V = V2; idx = i; }
    else if (i < n2 + n3) { keys = keys3; vals = vals3; K = K3; V = V3; idx = i - n2; }
    else return;
    unsigned k = (unsigned)keys[idx];
    if (k == EMPTY) { atomicOr(&flags[1], 1); return; }  // can't represent: fallback
    unsigned slot = bucket_of(k) * 4u;
    for (;;) {
        unsigned prev = atomicCAS(&K[slot], EMPTY, k);
        if (prev == EMPTY) { V[slot] = vals[idx]; break; }
        slot = (slot + 1u) & SLOT_MASK;
    }
}

// ---------------- bucketized probe -----------------------------------------
__device__ __forceinline__ int resolve(uint4 q, const uint4* __restrict__ Kb,
                                       const int* __restrict__ V,
                                       unsigned key, unsigned b) {
    for (;;) {
        if (q.x == key)   return V[4u * b + 0u];
        if (q.x == EMPTY) return 0;
        if (q.y == key)   return V[4u * b + 1u];
        if (q.y == EMPTY) return 0;
        if (q.z == key)   return V[4u * b + 2u];
        if (q.z == EMPTY) return 0;
        if (q.w == key)   return V[4u * b + 3u];
        if (q.w == EMPTY) return 0;
        b = (b + 1u) & BUCKET_MASK;
        q = Kb[b];
    }
}

// ---------------- binary-search fallback ----------------------------------
template <typename K>
__device__ __forceinline__ int lower_bound(const K* __restrict__ keys, int n, K key) {
    int lo = 0, hi = n;
    while (lo < hi) {
        int mid = (lo + hi) >> 1;
        if (keys[mid] < key) lo = mid + 1; else hi = mid;
    }
    return lo;
}

template <typename K>
__device__ __forceinline__ K bprobe(const K* __restrict__ keys,
                                    const K* __restrict__ vals, int n, K key) {
    int idx = lower_bound(keys, n, key);
    if (idx >= n) idx = n - 1;
    return (keys[idx] == key) ? vals[idx] : (K)0;
}

// ---------------- main lookup: 4 elements/thread ---------------------------
__global__ __launch_bounds__(256) void ngram_hash_kernel(
    const void* __restrict__ xv,
    const unsigned* __restrict__ K2, const int* __restrict__ V2,
    const unsigned* __restrict__ K3, const int* __restrict__ V3,
    const void* __restrict__ k2v, const void* __restrict__ v2v,
    const void* __restrict__ k3v, const void* __restrict__ v3v,
    void* __restrict__ outv,
    int n2, int n3, int S, int total, const int* __restrict__ flags)
{
    int gid = blockIdx.x * blockDim.x + threadIdx.x;
    int base = gid * 4;
    if (base >= total) return;

    if (flags[0]) {
        // int64 layout (x64-enabled harness): binary-search path
        const long long* x = (const long long*)xv;
        long long* out = (long long*)outv;
        for (int i = 0; i < 4 && base + i < total; ++i) {
            int g = base + i;
            int s = g & (S - 1);
            long long t2 = x[g];
            long long t1 = (s >= 1) ? x[g - 1] : 0ll;
            long long t0 = (s >= 2) ? x[g - 2] : 0ll;
            long long e2 = (t1 << BASE_BITS) | t2;
            long long e3 = (((t0 << BASE_BITS) | t1) << BASE_BITS) | t2;
            out[g]         = bprobe((const long long*)k2v, (const long long*)v2v, n2, e2);
            out[total + g] = bprobe((const long long*)k3v, (const long long*)v3v, n3, e3);
        }
        return;
    }
    if (flags[1]) {
        // sentinel collision (shouldn't happen for this data): int32 bsearch
        const int* x = (const int*)xv;
        int* out = (int*)outv;
        for (int i = 0; i < 4 && base + i < total; ++i) {
            int g = base + i;
            int s = g & (S - 1);
            unsigned t2 = (unsigned)x[g];
            unsigned t1 = (s >= 1) ? (unsigned)x[g - 1] : 0u;
            unsigned t0 = (s >= 2) ? (unsigned)x[g - 2] : 0u;
            int e2 = (int)((t1 << BASE_BITS) | t2);
            int e3 = (int)((((t0 << BASE_BITS) | t1) << BASE_BITS) | t2);
            out[g]         = bprobe((const int*)k2v, (const int*)v2v, n2, e2);
            out[total + g] = bprobe((const int*)k3v, (const int*)v3v, n3, e3);
        }
        return;
    }

    const int* x = (const int*)xv;
    const uint4* KB2 = (const uint4*)K2;
    const uint4* KB3 = (const uint4*)K3;

    if (base + 3 < total) {
        int4 xq = ((const int4*)x)[gid];
        int sb = base & (S - 1);
        unsigned t[6];
        t[0] = (sb != 0) ? (unsigned)x[base - 2] : 0u;
        t[1] = (sb != 0) ? (unsigned)x[base - 1] : 0u;
        t[2] = (unsigned)xq.x; t[3] = (unsigned)xq.y;
        t[4] = (unsigned)xq.z; t[5] = (unsigned)xq.w;

        unsigned e2[4], e3[4], b2[4], b3[4];
        #pragma unroll
        for (int i = 0; i < 4; ++i) {
            unsigned t0 = t[i], t1 = t[i + 1], t2 = t[i + 2];
            e2[i] = (t1 << BASE_BITS) | t2;
            e3[i] = (((t0 << BASE_BITS) | t1) << BASE_BITS) | t2;
            b2[i] = bucket_of(e2[i]);
            b3[i] = bucket_of(e3[i]);
        }
        // issue all 8 initial bucket loads before resolving (MLP)
        uint4 q2[4], q3[4];
        #pragma unroll
        for (int i = 0; i < 4; ++i) { q2[i] = KB2[b2[i]]; q3[i] = KB3[b3[i]]; }

        int4 r2, r3;
        r2.x = resolve(q2[0], KB2, V2, e2[0], b2[0]);
        r2.y = resolve(q2[1], KB2, V2, e2[1], b2[1]);
        r2.z = resolve(q2[2], KB2, V2, e2[2], b2[2]);
        r2.w = resolve(q2[3], KB2, V2, e2[3], b2[3]);
        r3.x = resolve(q3[0], KB3, V3, e3[0], b3[0]);
        r3.y = resolve(q3[1], KB3, V3, e3[1], b3[1]);
        r3.z = resolve(q3[2], KB3, V3, e3[2], b3[2]);
        r3.w = resolve(q3[3], KB3, V3, e3[3], b3[3]);

        ((int4*)outv)[gid] = r2;
        ((int4*)outv)[total / 4 + gid] = r3;
    } else {
        int* out = (int*)outv;
        for (int i = 0; i < 4 && base + i < total; ++i) {
            int g = base + i;
            int s = g & (S - 1);
            unsigned t2 = (unsigned)x[g];
            unsigned t1 = (s >= 1) ? (unsigned)x[g - 1] : 0u;
            unsigned t0 = (s >= 2) ? (unsigned)x[g - 2] : 0u;
            unsigned e2 = (t1 << BASE_BITS) | t2;
            unsigned e3 = (((t0 << BASE_BITS) | t1) << BASE_BITS) | t2;
            unsigned bb2 = bucket_of(e2), bb3 = bucket_of(e3);
            out[g]         = resolve(KB2[bb2], KB2, V2, e2, bb2);
            out[total + g] = resolve(KB3[bb3], KB3, V3, e3, bb3);
        }
    }
}

extern "C" void kernel_launch(void* const* d_in, const int* in_sizes, int n_in,
                              void* d_out, int out_size, void* d_ws, size_t ws_size,
                              hipStream_t stream) {
    const void* x  = d_in[0];
    const void* k2 = d_in[1];
    const void* v2 = d_in[2];
    const void* k3 = d_in[3];
    const void* v3 = d_in[4];
    int n2 = in_sizes[1];
    int n3 = in_sizes[3];
    int total = in_sizes[0];     // B * S = 4,194,304
    int S = 16384;

    int* flags = (int*)d_ws;
    detect_dtype_kernel<<<1, 256, 0, stream>>>((const unsigned int*)x, flags);

    size_t key_bytes = (size_t)NSLOTS * 4;          // 1MB per table
    size_t need = 256 + 4 * key_bytes;              // K2,K3,V2,V3

    int block = 256;

    if (ws_size >= need) {
        unsigned* K2 = (unsigned*)((char*)d_ws + 256);
        unsigned* K3 = K2 + NSLOTS;
        int* V2 = (int*)(K3 + NSLOTS);
        int* V3 = V2 + NSLOTS;

        // fill both key tables (2MB contiguous) with EMPTY
        init_keys_kernel<<<512, 256, 0, stream>>>((uint4*)K2, (int)(2 * NSLOTS / 4));

        build_hash_kernel<<<(n2 + n3 + 255) / 256, 256, 0, stream>>>(
            (const int*)k2, (const int*)v2, n2,
            (const int*)k3, (const int*)v3, n3,
            K2, V2, K3, V3, flags);

        int grid = (total / 4 + block - 1) / block;
        ngram_hash_kernel<<<grid, block, 0, stream>>>(
            x, K2, V2, K3, V3, k2, v2, k3, v3, d_out, n2, n3, S, total, flags);
    } else {
        // ws too small: plain bsearch via the same kernel's fallback flag
        // (force fallback by setting flags[1] via a tiny kernel is overkill;
        //  instead reuse hash kernel only when tables exist)
        int grid = (total / 4 + block - 1) / block;
        // Use null tables is unsafe; emulate with bsearch-only kernel:
        // flags[1] may be 0, so launch a dedicated path: set flags[1]=1 via
        // hipMemsetAsync on the second int.
        hipMemsetAsync((char*)d_ws + 4, 0xFF, 4, stream);  // flags[1] != 0
        ngram_hash_kernel<<<grid, block, 0, stream>>>(
            x, nullptr, nullptr, nullptr, nullptr,
            k2, v2, k3, v3, d_out, n2, n3, S, total, flags);
    }
}

// Round 5
// 93.197 us; speedup vs baseline: 3.8523x; 1.2562x over previous
//
#include <hip/hip_runtime.h>

#define BASE_BITS 17
#define BUCKET_LOG 16
#define NBUCKETS (1u << BUCKET_LOG)          // 65536 buckets x 4 slots = 1MB/table
#define NSLOTS (NBUCKETS * 4u)
#define SLOT_MASK (NSLOTS - 1u)
#define BUCKET_MASK (NBUCKETS - 1u)
#define EMPTY 0xFFFFFFFFu

typedef int  iv4 __attribute__((ext_vector_type(4)));
typedef unsigned uv4 __attribute__((ext_vector_type(4)));

__device__ __forceinline__ unsigned bucket_of(unsigned k) {
    return (k * 2654435761u) >> (32 - BUCKET_LOG);
}

// Pure-register bucket match. Linear-probing invariant: along the probe
// sequence from a key's home slot there is no EMPTY before the key, so
// (any match -> hit), (any EMPTY & no match -> miss), (full & no match -> continue).
// Returns slot index >=0 on hit, -2 on miss, -1 on continue.
__device__ __forceinline__ int match4(uv4 q, unsigned e, unsigned b) {
    int slot = -1;
    slot = (q.w == e) ? (int)(b * 4u + 3u) : slot;
    slot = (q.z == e) ? (int)(b * 4u + 2u) : slot;
    slot = (q.y == e) ? (int)(b * 4u + 1u) : slot;
    slot = (q.x == e) ? (int)(b * 4u + 0u) : slot;
    if (slot >= 0) return slot;
    unsigned mx = max(max(q.x, q.y), max(q.z, q.w));  // EMPTY is max u32
    return (mx == EMPTY) ? -2 : -1;
}

// ---------------- dtype detect (fallback path only) ------------------------
// flags[0]=1 => int32 layout (some odd 32-bit word of x is nonzero)
__global__ void detect_dtype_kernel(const unsigned* __restrict__ xw,
                                    int* __restrict__ flags) {
    if (xw[2 * threadIdx.x + 1] != 0u) atomicOr(&flags[0], 1);
}

// ---------------- build (with inline dtype detect) --------------------------
__global__ void build_hash_kernel(const int* __restrict__ keys2,
                                  const int* __restrict__ vals2, int n2,
                                  const int* __restrict__ keys3,
                                  const int* __restrict__ vals3, int n3,
                                  const unsigned* __restrict__ xw,
                                  unsigned* __restrict__ K2, int* __restrict__ V2,
                                  unsigned* __restrict__ K3, int* __restrict__ V3,
                                  int* __restrict__ flags) {
    int i = blockIdx.x * blockDim.x + threadIdx.x;
    if (i < 256 && xw[2 * i + 1] != 0u) atomicOr(&flags[0], 1);  // int32 layout

    const int* keys; const int* vals; unsigned* K; int* V; int idx;
    if (i < n2)           { keys = keys2; vals = vals2; K = K2; V = V2; idx = i; }
    else if (i < n2 + n3) { keys = keys3; vals = vals3; K = K3; V = V3; idx = i - n2; }
    else return;
    unsigned k = (unsigned)keys[idx];
    if (k == EMPTY) { atomicOr(&flags[1], 1); return; }  // sentinel collision
    unsigned slot = bucket_of(k) * 4u;
    for (;;) {
        unsigned prev = atomicCAS(&K[slot], EMPTY, k);
        if (prev == EMPTY) { V[slot] = vals[idx]; break; }
        slot = (slot + 1u) & SLOT_MASK;
    }
}

// ---------------- binary-search fallback helpers ---------------------------
template <typename K>
__device__ __forceinline__ int lower_bound(const K* __restrict__ keys, int n, K key) {
    int lo = 0, hi = n;
    while (lo < hi) {
        int mid = (lo + hi) >> 1;
        if (keys[mid] < key) lo = mid + 1; else hi = mid;
    }
    return lo;
}

template <typename K>
__device__ __forceinline__ K bprobe(const K* __restrict__ keys,
                                    const K* __restrict__ vals, int n, K key) {
    int idx = lower_bound(keys, n, key);
    if (idx >= n) idx = n - 1;
    return (keys[idx] == key) ? vals[idx] : (K)0;
}

// ---------------- main lookup: 4 elems/thread, 8 parallel probes -----------
__global__ __launch_bounds__(256) void ngram_hash_kernel(
    const void* __restrict__ xv,
    const unsigned* __restrict__ K2, const int* __restrict__ V2,
    const unsigned* __restrict__ K3, const int* __restrict__ V3,
    const void* __restrict__ k2v, const void* __restrict__ v2v,
    const void* __restrict__ k3v, const void* __restrict__ v3v,
    void* __restrict__ outv,
    int n2, int n3, int S, int total, const int* __restrict__ flags)
{
    int gid = blockIdx.x * blockDim.x + threadIdx.x;
    int base = gid * 4;
    if (base >= total) return;
    int f0 = flags[0], f1 = flags[1];

    if (!f0) {
        // int64 layout (x64-enabled harness): binary-search path
        const long long* x = (const long long*)xv;
        long long* out = (long long*)outv;
        for (int i = 0; i < 4 && base + i < total; ++i) {
            int g = base + i;
            int s = g & (S - 1);
            long long t2 = x[g];
            long long t1 = (s >= 1) ? x[g - 1] : 0ll;
            long long t0 = (s >= 2) ? x[g - 2] : 0ll;
            long long e2 = (t1 << BASE_BITS) | t2;
            long long e3 = (((t0 << BASE_BITS) | t1) << BASE_BITS) | t2;
            out[g]         = bprobe((const long long*)k2v, (const long long*)v2v, n2, e2);
            out[total + g] = bprobe((const long long*)k3v, (const long long*)v3v, n3, e3);
        }
        return;
    }
    if (f1) {
        // hash tables unusable: int32 binary search
        const int* x = (const int*)xv;
        int* out = (int*)outv;
        for (int i = 0; i < 4 && base + i < total; ++i) {
            int g = base + i;
            int s = g & (S - 1);
            unsigned t2 = (unsigned)x[g];
            unsigned t1 = (s >= 1) ? (unsigned)x[g - 1] : 0u;
            unsigned t0 = (s >= 2) ? (unsigned)x[g - 2] : 0u;
            int e2 = (int)((t1 << BASE_BITS) | t2);
            int e3 = (int)((((t0 << BASE_BITS) | t1) << BASE_BITS) | t2);
            out[g]         = bprobe((const int*)k2v, (const int*)v2v, n2, e2);
            out[total + g] = bprobe((const int*)k3v, (const int*)v3v, n3, e3);
        }
        return;
    }

    // ---------- hash fast path ----------
    const int* x = (const int*)xv;
    iv4 xq = __builtin_nontemporal_load(&((const iv4*)x)[gid]);
    int sb = base & (S - 1);
    unsigned t[6];
    t[0] = (sb != 0) ? (unsigned)x[base - 2] : 0u;
    t[1] = (sb != 0) ? (unsigned)x[base - 1] : 0u;
    t[2] = (unsigned)xq.x; t[3] = (unsigned)xq.y;
    t[4] = (unsigned)xq.z; t[5] = (unsigned)xq.w;

    unsigned e[8], b[8];
    #pragma unroll
    for (int i = 0; i < 4; ++i) {
        unsigned t0 = t[i], t1 = t[i + 1], t2 = t[i + 2];
        e[i]     = (t1 << BASE_BITS) | t2;                        // 2-gram
        e[i + 4] = (((t0 << BASE_BITS) | t1) << BASE_BITS) | t2;  // 3-gram
    }
    #pragma unroll
    for (int i = 0; i < 8; ++i) b[i] = bucket_of(e[i]);

    const uv4* KB2 = (const uv4*)K2;
    const uv4* KB3 = (const uv4*)K3;

    // Phase 1: issue all 8 home-bucket gathers, then pure-register match.
    uv4 q[8];
    #pragma unroll
    for (int i = 0; i < 8; ++i) q[i] = (i < 4 ? KB2 : KB3)[b[i]];

    int st[8];
    #pragma unroll
    for (int i = 0; i < 8; ++i) st[i] = match4(q[i], e[i], b[i]);

    // Phase 2: rare combined retry loop (all unresolved probes advance together).
    bool cont = false;
    #pragma unroll
    for (int i = 0; i < 8; ++i) cont |= (st[i] == -1);
    while (__any(cont)) {
        #pragma unroll
        for (int i = 0; i < 8; ++i) {
            if (st[i] == -1) {
                b[i] = (b[i] + 1u) & BUCKET_MASK;
                uv4 nq = (i < 4 ? KB2 : KB3)[b[i]];
                st[i] = match4(nq, e[i], b[i]);
            }
        }
        cont = false;
        #pragma unroll
        for (int i = 0; i < 8; ++i) cont |= (st[i] == -1);
    }

    // Phase 3: predicated value loads (hits are ~2.4%).
    int r[8];
    #pragma unroll
    for (int i = 0; i < 8; ++i)
        r[i] = (st[i] >= 0) ? (i < 4 ? V2 : V3)[st[i]] : 0;

    iv4 o2 = { r[0], r[1], r[2], r[3] };
    iv4 o3 = { r[4], r[5], r[6], r[7] };
    __builtin_nontemporal_store(o2, &((iv4*)outv)[gid]);
    __builtin_nontemporal_store(o3, &((iv4*)outv)[total / 4 + gid]);
}

extern "C" void kernel_launch(void* const* d_in, const int* in_sizes, int n_in,
                              void* d_out, int out_size, void* d_ws, size_t ws_size,
                              hipStream_t stream) {
    const void* x  = d_in[0];
    const void* k2 = d_in[1];
    const void* v2 = d_in[2];
    const void* k3 = d_in[3];
    const void* v3 = d_in[4];
    int n2 = in_sizes[1];
    int n3 = in_sizes[3];
    int total = in_sizes[0];     // B * S = 4,194,304 (divisible by 4)
    int S = 16384;

    int* flags = (int*)d_ws;
    size_t key_bytes = (size_t)NSLOTS * 4;          // 1MB per table
    size_t need = 256 + 4 * key_bytes;              // K2,K3,V2,V3

    int block = 256;
    int grid = (total / 4 + block - 1) / block;

    if (ws_size >= need) {
        unsigned* K2 = (unsigned*)((char*)d_ws + 256);
        unsigned* K3 = K2 + NSLOTS;
        int* V2 = (int*)(K3 + NSLOTS);
        int* V3 = V2 + NSLOTS;

        (void)hipMemsetAsync(flags, 0, 16, stream);             // flags = 0
        (void)hipMemsetAsync(K2, 0xFF, 2 * key_bytes, stream);  // keys = EMPTY

        build_hash_kernel<<<(n2 + n3 + 255) / 256, 256, 0, stream>>>(
            (const int*)k2, (const int*)v2, n2,
            (const int*)k3, (const int*)v3, n3,
            (const unsigned*)x, K2, V2, K3, V3, flags);

        ngram_hash_kernel<<<grid, block, 0, stream>>>(
            x, K2, V2, K3, V3, k2, v2, k3, v3, d_out, n2, n3, S, total, flags);
    } else {
        // ws too small for tables: detect dtype, force bsearch path
        (void)hipMemsetAsync(flags, 0, 16, stream);
        detect_dtype_kernel<<<1, 256, 0, stream>>>((const unsigned*)x, flags);
        (void)hipMemsetAsync((char*)d_ws + 4, 0xFF, 4, stream);  // flags[1] != 0
        ngram_hash_kernel<<<grid, block, 0, stream>>>(
            x, nullptr, nullptr, nullptr, nullptr,
            k2, v2, k3, v3, d_out, n2, n3, S, total, flags);
    }
}